// Round 1
// baseline (317.854 us; speedup 1.0000x reference)
//
#include <hip/hip_runtime.h>

#define TT 512   // timesteps
#define ID 32    // input features
#define HD 64    // hidden
#define GD 256   // 4*H gates
#define CH 32    // x-staging chunk (timesteps per LDS refill)
#define NT 8     // tickers

__device__ __forceinline__ float sigm(float x) {
    // 1/(1+2^(-x*log2e)) -- v_exp_f32 + v_rcp_f32, ~1ulp each
    return __builtin_amdgcn_rcpf(1.0f + __builtin_amdgcn_exp2f(-1.44269504089f * x));
}
__device__ __forceinline__ float tanhfast(float x) {
    // tanh(x) = 1 - 2/(2^(2x*log2e)+1)
    return fmaf(-2.0f, __builtin_amdgcn_rcpf(1.0f + __builtin_amdgcn_exp2f(2.88539008178f * x)), 1.0f);
}

__global__ __launch_bounds__(256, 2) void lstm_fused(
    const float* __restrict__ x,      // (B, T, I)
    const float* __restrict__ w_ih,   // (4H, I)
    const float* __restrict__ w_hh,   // (4H, H)
    const float* __restrict__ b_ih,   // (4H)
    const float* __restrict__ b_hh,   // (4H)
    const float* __restrict__ w_fc,   // (NT, H)
    const float* __restrict__ b_fc,   // (NT)
    float* __restrict__ out)          // (B, NT)
{
    const int row = blockIdx.x;
    const int g   = threadIdx.x;      // gate index 0..255

    __shared__ float s_h[HD];         // hidden state (broadcast-read)
    __shared__ float s_gates[GD];     // activated gates for the update phase
    __shared__ float s_x[CH * ID];    // staged x chunk (32 steps)

    // --- step-invariant weights into registers: 64 + 32 fp32 per thread ---
    float wh[HD];
    {
        const float4* src = (const float4*)(w_hh + (size_t)g * HD);
        float4* dst = (float4*)wh;
        #pragma unroll
        for (int k = 0; k < HD / 4; k++) dst[k] = src[k];
    }
    float wi[ID];
    {
        const float4* src = (const float4*)(w_ih + (size_t)g * ID);
        float4* dst = (float4*)wi;
        #pragma unroll
        for (int i = 0; i < ID / 4; i++) dst[i] = src[i];
    }
    const float bias = b_ih[g] + b_hh[g];

    float c_reg = 0.0f;               // thread j<64 owns c[j]
    if (g < HD) s_h[g] = 0.0f;

    const float* xrow = x + (size_t)row * (TT * ID);
    __syncthreads();

    for (int t = 0; t < TT; t++) {
        if ((t & (CH - 1)) == 0) {
            // stage CH*ID = 1024 floats with 256 coalesced float4 loads
            ((float4*)s_x)[g] = ((const float4*)(xrow + t * ID))[g];
            __syncthreads();
        }
        const float* xt = s_x + (t & (CH - 1)) * ID;

        // gate[g] = bias + h . w_hh[g,:] + x_t . w_ih[g,:]
        float a0 = bias, a1 = 0.0f, a2 = 0.0f, a3 = 0.0f;
        #pragma unroll
        for (int k = 0; k < HD / 4; k++) {
            float4 h4 = ((const float4*)s_h)[k];      // ds_read_b128, broadcast
            a0 = fmaf(h4.x, wh[4*k+0], a0);
            a1 = fmaf(h4.y, wh[4*k+1], a1);
            a2 = fmaf(h4.z, wh[4*k+2], a2);
            a3 = fmaf(h4.w, wh[4*k+3], a3);
        }
        #pragma unroll
        for (int i = 0; i < ID / 4; i++) {
            float4 x4 = ((const float4*)xt)[i];       // ds_read_b128, broadcast
            a0 = fmaf(x4.x, wi[4*i+0], a0);
            a1 = fmaf(x4.y, wi[4*i+1], a1);
            a2 = fmaf(x4.z, wi[4*i+2], a2);
            a3 = fmaf(x4.w, wi[4*i+3], a3);
        }
        const float gate = (a0 + a1) + (a2 + a3);

        // wave-uniform activation: wave 2 (g in [128,192)) = tanh, else sigmoid
        float act;
        if ((g >> 6) == 2) act = tanhfast(gate);
        else               act = sigm(gate);
        s_gates[g] = act;
        __syncthreads();   // all h reads done; gates visible

        if (g < HD) {
            const float ig = s_gates[g];
            const float fg = s_gates[g + HD];
            const float gg = s_gates[g + 2 * HD];
            const float og = s_gates[g + 3 * HD];
            c_reg = fmaf(fg, c_reg, ig * gg);
            s_h[g] = og * tanhfast(c_reg);
        }
        __syncthreads();   // new h visible
    }

    // FC head: out[row, k] = h . w_fc[k,:] + b_fc[k]
    if (g < NT) {
        float acc = b_fc[g];
        const float* wf = w_fc + g * HD;
        #pragma unroll
        for (int j = 0; j < HD; j++) acc = fmaf(s_h[j], wf[j], acc);
        out[row * NT + g] = acc;
    }
}

extern "C" void kernel_launch(void* const* d_in, const int* in_sizes, int n_in,
                              void* d_out, int out_size, void* d_ws, size_t ws_size,
                              hipStream_t stream) {
    const float* x    = (const float*)d_in[0];
    const float* w_ih = (const float*)d_in[1];
    const float* w_hh = (const float*)d_in[2];
    const float* b_ih = (const float*)d_in[3];
    const float* b_hh = (const float*)d_in[4];
    const float* w_fc = (const float*)d_in[5];
    const float* b_fc = (const float*)d_in[6];
    float* out = (float*)d_out;

    const int B = in_sizes[0] / (TT * ID);   // 512
    lstm_fused<<<dim3(B), dim3(256), 0, stream>>>(x, w_ih, w_hh, b_ih, b_hh,
                                                  w_fc, b_fc, out);
}

// Round 2
// 215.159 us; speedup vs baseline: 1.4773x; 1.4773x over previous
//
#include <hip/hip_runtime.h>

#define TT 512   // timesteps
#define ID 32    // input features
#define HD 64    // hidden
#define NTK 8    // tickers

typedef __attribute__((ext_vector_type(8))) _Float16 half8;
typedef __attribute__((ext_vector_type(4))) float f32x4;
typedef __attribute__((ext_vector_type(2))) _Float16 half2v;

__device__ __forceinline__ float sigm(float x) {
    return __builtin_amdgcn_rcpf(1.0f + __builtin_amdgcn_exp2f(-1.44269504089f * x));
}
__device__ __forceinline__ float tanhfast(float x) {
    return fmaf(-2.0f, __builtin_amdgcn_rcpf(1.0f + __builtin_amdgcn_exp2f(2.88539008178f * x)), 1.0f);
}

// One block per batch row. gates(256) = [h|x](96) @ [W_hh|W_ih]^T via
// mfma_f32_16x16x32_f16. All 16 A-rows are fed the same z vector, so every
// C row is a duplicate of the matvec result; we use reg 0 in each lane.
// Wave w owns gate-columns j in [16w, 16w+16).
__global__ __launch_bounds__(256, 2) void lstm_mfma(
    const float* __restrict__ x,      // (B, T, I)
    const float* __restrict__ w_ih,   // (4H, I)
    const float* __restrict__ w_hh,   // (4H, H)
    const float* __restrict__ b_ih,   // (4H)
    const float* __restrict__ b_hh,   // (4H)
    const float* __restrict__ w_fc,   // (NTK, H)
    const float* __restrict__ b_fc,   // (NTK)
    float* __restrict__ out)          // (B, NTK)
{
    const int tid = threadIdx.x;
    const int wv  = tid >> 6;         // wave 0..3
    const int l   = tid & 63;
    const int l15 = l & 15;
    const int lq  = l >> 4;
    const int row = blockIdx.x;

    __shared__ __align__(16) _Float16 zbuf[2][8][8];  // [buf][k>>3][k&7], h part of z
    __shared__ float hfin[HD];

    // --- B fragments (W^T tiles) into registers, f16. ---
    // B layout for 16x16x32: col n = lane&15, k = (lane>>4)*8 + j.
    // k in [0,64): W_hh[n][k]; k in [64,96): W_ih[n][k-64].
    half8 Bf[3][4];
    float bias[4];
    #pragma unroll
    for (int nt = 0; nt < 4; ++nt) {
        const int n = nt * 64 + wv * 16 + l15;        // global gate index
        bias[nt] = b_ih[n] + b_hh[n];
        #pragma unroll
        for (int kt = 0; kt < 3; ++kt) {
            const float* src = (kt < 2) ? (w_hh + n * HD + kt * 32 + lq * 8)
                                        : (w_ih + n * ID + lq * 8);
            float4 p0 = ((const float4*)src)[0];
            float4 p1 = ((const float4*)src)[1];
            Bf[kt][nt] = (half8){(_Float16)p0.x, (_Float16)p0.y, (_Float16)p0.z, (_Float16)p0.w,
                                 (_Float16)p1.x, (_Float16)p1.y, (_Float16)p1.z, (_Float16)p1.w};
        }
    }

    if (tid < 64) ((_Float16*)zbuf)[tid] = (_Float16)0.0f;   // zbuf[0] = h(0) = 0

    // x prefetch: all lanes hold x[row][t][lq*8 .. lq*8+8) (rows duplicate)
    const float* xbase = x + (size_t)row * (TT * ID) + lq * 8;
    float4 xa = ((const float4*)xbase)[0];
    float4 xb = ((const float4*)xbase)[1];

    float c_ = 0.0f;
    __syncthreads();

    for (int t = 0; t < TT; ++t) {
        const int cur = t & 1;

        // A fragments: row m = lane&15 (all rows read the same z -> duplicates)
        half8 A0 = *(const half8*)&zbuf[cur][lq][0];        // k 0..31 chunk lq
        half8 A1 = *(const half8*)&zbuf[cur][4 + lq][0];    // k 32..63
        half8 A2 = (half8){(_Float16)xa.x, (_Float16)xa.y, (_Float16)xa.z, (_Float16)xa.w,
                           (_Float16)xb.x, (_Float16)xb.y, (_Float16)xb.z, (_Float16)xb.w};

        // prefetch next step's x while MFMA/act run
        {
            const int tn = (t + 1 < TT) ? (t + 1) : t;
            const float4* p = (const float4*)(xbase + (size_t)tn * ID);
            xa = p[0]; xb = p[1];
        }

        f32x4 acc[4];
        #pragma unroll
        for (int nt = 0; nt < 4; ++nt) {
            acc[nt] = (f32x4){bias[nt], bias[nt], bias[nt], bias[nt]};
            acc[nt] = __builtin_amdgcn_mfma_f32_16x16x32_f16(A0, Bf[0][nt], acc[nt], 0, 0, 0);
            acc[nt] = __builtin_amdgcn_mfma_f32_16x16x32_f16(A1, Bf[1][nt], acc[nt], 0, 0, 0);
            acc[nt] = __builtin_amdgcn_mfma_f32_16x16x32_f16(A2, Bf[2][nt], acc[nt], 0, 0, 0);
        }

        // gate for column j = 16*wv + l15 is in reg 0 (row 0 duplicate)
        const float ig = sigm(acc[0][0]);
        const float fg = sigm(acc[1][0]);
        const float gg = tanhfast(acc[2][0]);
        const float og = sigm(acc[3][0]);
        c_ = fmaf(fg, c_, ig * gg);
        const float h_ = og * tanhfast(c_);

        const float ho = __shfl_xor(h_, 1);     // partner column j^1

        if (t == TT - 1 && l < 16) hfin[wv * 16 + l15] = h_;

        if (l < 16 && !(l & 1)) {
            const int j = wv * 16 + l15;        // even
            *(half2v*)&zbuf[cur ^ 1][j >> 3][j & 7] = (half2v){(_Float16)h_, (_Float16)ho};
        }
        __syncthreads();
    }

    // FC head: out[row, tk] = h . w_fc[tk,:] + b_fc[tk]
    if (tid < 64) {
        const int tk = tid & 7;
        const int q  = tid >> 3;
        const float* wf = w_fc + tk * HD + q * 8;
        const float* hv = hfin + q * 8;
        float a = 0.0f;
        #pragma unroll
        for (int j2 = 0; j2 < 8; ++j2) a = fmaf(hv[j2], wf[j2], a);
        a += __shfl_xor(a, 8);
        a += __shfl_xor(a, 16);
        a += __shfl_xor(a, 32);
        if (q == 0) out[row * NTK + tk] = a + b_fc[tk];
    }
}

extern "C" void kernel_launch(void* const* d_in, const int* in_sizes, int n_in,
                              void* d_out, int out_size, void* d_ws, size_t ws_size,
                              hipStream_t stream) {
    const float* x    = (const float*)d_in[0];
    const float* w_ih = (const float*)d_in[1];
    const float* w_hh = (const float*)d_in[2];
    const float* b_ih = (const float*)d_in[3];
    const float* b_hh = (const float*)d_in[4];
    const float* w_fc = (const float*)d_in[5];
    const float* b_fc = (const float*)d_in[6];
    float* out = (float*)d_out;

    const int B = in_sizes[0] / (TT * ID);   // 512
    lstm_mfma<<<dim3(B), dim3(256), 0, stream>>>(x, w_ih, w_hh, b_ih, b_hh,
                                                 w_fc, b_fc, out);
}

// Round 3
// 179.342 us; speedup vs baseline: 1.7723x; 1.1997x over previous
//
#include <hip/hip_runtime.h>

#define TT 512   // timesteps
#define ID 32    // input features
#define HD 64    // hidden
#define NTK 8    // tickers

typedef __attribute__((ext_vector_type(8))) _Float16 half8;
typedef __attribute__((ext_vector_type(4))) float f32x4;

__device__ __forceinline__ float sigm(float x) {
    return __builtin_amdgcn_rcpf(1.0f + __builtin_amdgcn_exp2f(-1.44269504089f * x));
}
__device__ __forceinline__ float tanhfast(float x) {
    return fmaf(-2.0f, __builtin_amdgcn_rcpf(1.0f + __builtin_amdgcn_exp2f(2.88539008178f * x)), 1.0f);
}

// Pre-pass: x f32 -> f16 (one half8 per thread)
__global__ void cvt_x(const float* __restrict__ x, _Float16* __restrict__ xo, int n8) {
    int i = blockIdx.x * blockDim.x + threadIdx.x;
    if (i >= n8) return;
    const float4* p = (const float4*)x + 2 * (size_t)i;
    float4 a = p[0], b = p[1];
    half8 o = {(_Float16)a.x, (_Float16)a.y, (_Float16)a.z, (_Float16)a.w,
               (_Float16)b.x, (_Float16)b.y, (_Float16)b.z, (_Float16)b.w};
    *((half8*)xo + i) = o;
}

// One block per batch row; wave w owns gate columns {64*nt + 16*w + (lane&15)}.
// gates(256) = [h|x](96) @ [W_hh|W_ih]^T via mfma_f32_16x16x32_f16 with all 16
// A-rows fed the same z (duplicate rows) -> every lane's C reg0 is the matvec
// value for its column. Bias is folded into a loop-invariant C-in; the x-MFMA
// initializes the chain and issues under the ds_read latency of the h tiles.
template <bool XF16>
__global__ __launch_bounds__(256, 2) void lstm_mfma(
    const float* __restrict__ x,       // (B, T, I) f32 (fallback path)
    const _Float16* __restrict__ xf,   // (B, T, I) f16 (fast path)
    const float* __restrict__ w_ih,    // (4H, I)
    const float* __restrict__ w_hh,    // (4H, H)
    const float* __restrict__ b_ih,    // (4H)
    const float* __restrict__ b_hh,    // (4H)
    const float* __restrict__ w_fc,    // (NTK, H)
    const float* __restrict__ b_fc,    // (NTK)
    float* __restrict__ out)           // (B, NTK)
{
    const int tid = threadIdx.x;
    const int wv  = tid >> 6;          // wave 0..3
    const int l   = tid & 63;
    const int l15 = l & 15;
    const int lq  = l >> 4;
    const int row = blockIdx.x;

    __shared__ __align__(16) _Float16 zbuf[2][HD];   // double-buffered h (f16)
    __shared__ float hfin[HD];

    // B fragments (W^T tiles) in registers, f16.
    // B layout: col n = lane&15, k = (lane>>4)*8 + j.
    half8 Bh0[4], Bh1[4], Bx[4];
    f32x4 biasC[4];
    #pragma unroll
    for (int nt = 0; nt < 4; ++nt) {
        const int n = nt * 64 + wv * 16 + l15;       // global gate index
        const float bias = b_ih[n] + b_hh[n];
        biasC[nt] = (f32x4){bias, bias, bias, bias};
        const float* h0 = w_hh + n * HD + lq * 8;
        const float* h1 = w_hh + n * HD + 32 + lq * 8;
        const float* xi = w_ih + n * ID + lq * 8;
        float4 p0 = ((const float4*)h0)[0], p1 = ((const float4*)h0)[1];
        Bh0[nt] = (half8){(_Float16)p0.x, (_Float16)p0.y, (_Float16)p0.z, (_Float16)p0.w,
                          (_Float16)p1.x, (_Float16)p1.y, (_Float16)p1.z, (_Float16)p1.w};
        p0 = ((const float4*)h1)[0]; p1 = ((const float4*)h1)[1];
        Bh1[nt] = (half8){(_Float16)p0.x, (_Float16)p0.y, (_Float16)p0.z, (_Float16)p0.w,
                          (_Float16)p1.x, (_Float16)p1.y, (_Float16)p1.z, (_Float16)p1.w};
        p0 = ((const float4*)xi)[0]; p1 = ((const float4*)xi)[1];
        Bx[nt]  = (half8){(_Float16)p0.x, (_Float16)p0.y, (_Float16)p0.z, (_Float16)p0.w,
                          (_Float16)p1.x, (_Float16)p1.y, (_Float16)p1.z, (_Float16)p1.w};
    }

    if (tid < HD) zbuf[0][tid] = (_Float16)0.0f;

    // x prefetch: lane holds x[row][t][lq*8 .. lq*8+8) (16-lane groups duplicate)
    const _Float16* xfb = xf + (size_t)row * (TT * ID) + lq * 8;
    const float*    x32 = x  + (size_t)row * (TT * ID) + lq * 8;
    half8 xa;
    if (XF16) {
        xa = *(const half8*)xfb;
    } else {
        float4 a = ((const float4*)x32)[0], b = ((const float4*)x32)[1];
        xa = (half8){(_Float16)a.x, (_Float16)a.y, (_Float16)a.z, (_Float16)a.w,
                     (_Float16)b.x, (_Float16)b.y, (_Float16)b.z, (_Float16)b.w};
    }

    float c_ = 0.0f;
    __syncthreads();

    for (int t = 0; t < TT; ++t) {
        const int cur = t & 1;

        half8 A2 = xa;
        // prefetch next x immediately (longest possible latency cover)
        {
            const int tn = (t + 1 < TT) ? (t + 1) : t;
            if (XF16) {
                xa = *(const half8*)(xfb + (size_t)tn * ID);
            } else {
                float4 a = ((const float4*)(x32 + (size_t)tn * ID))[0];
                float4 b = ((const float4*)(x32 + (size_t)tn * ID))[1];
                xa = (half8){(_Float16)a.x, (_Float16)a.y, (_Float16)a.z, (_Float16)a.w,
                             (_Float16)b.x, (_Float16)b.y, (_Float16)b.z, (_Float16)b.w};
            }
        }

        // h fragments (ds_read_b128; x-MFMAs below issue under this latency)
        half8 A0 = *(const half8*)&zbuf[cur][lq * 8];
        half8 A1 = *(const half8*)&zbuf[cur][32 + lq * 8];

        f32x4 acc[4];
        #pragma unroll
        for (int nt = 0; nt < 4; ++nt)
            acc[nt] = __builtin_amdgcn_mfma_f32_16x16x32_f16(A2, Bx[nt], biasC[nt], 0, 0, 0);
        #pragma unroll
        for (int nt = 0; nt < 4; ++nt)
            acc[nt] = __builtin_amdgcn_mfma_f32_16x16x32_f16(A0, Bh0[nt], acc[nt], 0, 0, 0);
        #pragma unroll
        for (int nt = 0; nt < 4; ++nt)
            acc[nt] = __builtin_amdgcn_mfma_f32_16x16x32_f16(A1, Bh1[nt], acc[nt], 0, 0, 0);

        const float ig = sigm(acc[0][0]);
        const float fg = sigm(acc[1][0]);
        const float gg = tanhfast(acc[2][0]);
        const float og = sigm(acc[3][0]);
        c_ = fmaf(fg, c_, ig * gg);
        const float h_ = og * tanhfast(c_);

        if (t == TT - 1 && l < 16) hfin[wv * 16 + l15] = h_;
        if (l < 16) zbuf[cur ^ 1][wv * 16 + l15] = (_Float16)h_;   // ds_write_b16
        __syncthreads();
    }

    // FC head: out[row, tk] = h . w_fc[tk,:] + b_fc[tk]
    if (tid < 64) {
        const int tk = tid & 7;
        const int q  = tid >> 3;
        const float* wf = w_fc + tk * HD + q * 8;
        const float* hv = hfin + q * 8;
        float a = 0.0f;
        #pragma unroll
        for (int j2 = 0; j2 < 8; ++j2) a = fmaf(hv[j2], wf[j2], a);
        a += __shfl_xor(a, 8);
        a += __shfl_xor(a, 16);
        a += __shfl_xor(a, 32);
        if (q == 0) out[row * NTK + tk] = a + b_fc[tk];
    }
}

extern "C" void kernel_launch(void* const* d_in, const int* in_sizes, int n_in,
                              void* d_out, int out_size, void* d_ws, size_t ws_size,
                              hipStream_t stream) {
    const float* x    = (const float*)d_in[0];
    const float* w_ih = (const float*)d_in[1];
    const float* w_hh = (const float*)d_in[2];
    const float* b_ih = (const float*)d_in[3];
    const float* b_hh = (const float*)d_in[4];
    const float* w_fc = (const float*)d_in[5];
    const float* b_fc = (const float*)d_in[6];
    float* out = (float*)d_out;

    const int nx = in_sizes[0];              // B*T*I
    const int B  = nx / (TT * ID);           // 512
    const size_t need = (size_t)nx * sizeof(_Float16);

    if (ws_size >= need) {
        _Float16* xf = (_Float16*)d_ws;
        const int n8 = nx / 8;
        cvt_x<<<dim3((n8 + 255) / 256), dim3(256), 0, stream>>>(x, xf, n8);
        lstm_mfma<true><<<dim3(B), dim3(256), 0, stream>>>(x, xf, w_ih, w_hh,
                                                           b_ih, b_hh, w_fc, b_fc, out);
    } else {
        lstm_mfma<false><<<dim3(B), dim3(256), 0, stream>>>(x, (const _Float16*)d_ws,
                                                            w_ih, w_hh, b_ih, b_hh,
                                                            w_fc, b_fc, out);
    }
}

// Round 4
// 151.217 us; speedup vs baseline: 2.1020x; 1.1860x over previous
//
#include <hip/hip_runtime.h>

#define TT 512   // timesteps
#define ID 32    // input features
#define HD 64    // hidden
#define NTK 8    // tickers

typedef __attribute__((ext_vector_type(8))) _Float16 half8;
typedef __attribute__((ext_vector_type(4))) float f32x4;

__device__ __forceinline__ float sigm(float x) {
    return __builtin_amdgcn_rcpf(1.0f + __builtin_amdgcn_exp2f(-1.44269504089f * x));
}
__device__ __forceinline__ float tanhfast(float x) {
    return fmaf(-2.0f, __builtin_amdgcn_rcpf(1.0f + __builtin_amdgcn_exp2f(2.88539008178f * x)), 1.0f);
}

// Pre-pass: x f32 -> f16 (one half8 per thread)
__global__ void cvt_x(const float* __restrict__ x, _Float16* __restrict__ xo, int n8) {
    int i = blockIdx.x * blockDim.x + threadIdx.x;
    if (i >= n8) return;
    const float4* p = (const float4*)x + 2 * (size_t)i;
    float4 a = p[0], b = p[1];
    half8 o = {(_Float16)a.x, (_Float16)a.y, (_Float16)a.z, (_Float16)a.w,
               (_Float16)b.x, (_Float16)b.y, (_Float16)b.z, (_Float16)b.w};
    *((half8*)xo + i) = o;
}

// TWO batch rows per block (A rows 0-7 = batch row 0, rows 8-15 = batch row 1;
// 8x duplication instead of 16x -> half the MFMA issue of round 3).
// 256 blocks x 4 waves = 1 block/CU, 1 wave/SIMD.
// Wave w owns gate columns {64*nt + 16*w + (lane&15)}; C rows m=lq*4+reg map
// to batch row lq>>1, so lane (lq,l15) activates (row lq>>1, its column).
template <bool XF16>
__global__ __launch_bounds__(256, 1) void lstm_mfma2(
    const float* __restrict__ x,       // (B, T, I) f32 (fallback)
    const _Float16* __restrict__ xf,   // (B, T, I) f16 (fast path)
    const float* __restrict__ w_ih,    // (4H, I)
    const float* __restrict__ w_hh,    // (4H, H)
    const float* __restrict__ b_ih,    // (4H)
    const float* __restrict__ b_hh,    // (4H)
    const float* __restrict__ w_fc,    // (NTK, H)
    const float* __restrict__ b_fc,    // (NTK)
    float* __restrict__ out)           // (B, NTK)
{
    const int tid = threadIdx.x;
    const int wv  = tid >> 6;          // wave 0..3
    const int l   = tid & 63;
    const int l15 = l & 15;
    const int lq  = l >> 4;
    const int r0  = blockIdx.x * 2;    // first of this block's two batch rows
    const int abr = l15 >> 3;          // A-fragment batch row for this lane's reads
    const int cbr = lq >> 1;           // C / activation batch row for this lane

    __shared__ __align__(16) _Float16 zbuf[2][2][HD];  // [buf][row][h]
    __shared__ float hfin[2][HD];

    // B fragments (W^T tiles) in registers, f16. col n = lane&15, k=(lane>>4)*8+j.
    half8 Bh0[4], Bh1[4], Bx[4];
    f32x4 biasC[4];
    #pragma unroll
    for (int nt = 0; nt < 4; ++nt) {
        const int n = nt * 64 + wv * 16 + l15;
        const float bias = b_ih[n] + b_hh[n];
        biasC[nt] = (f32x4){bias, bias, bias, bias};
        const float* h0 = w_hh + n * HD + lq * 8;
        const float* h1 = w_hh + n * HD + 32 + lq * 8;
        const float* xi = w_ih + n * ID + lq * 8;
        float4 p0 = ((const float4*)h0)[0], p1 = ((const float4*)h0)[1];
        Bh0[nt] = (half8){(_Float16)p0.x, (_Float16)p0.y, (_Float16)p0.z, (_Float16)p0.w,
                          (_Float16)p1.x, (_Float16)p1.y, (_Float16)p1.z, (_Float16)p1.w};
        p0 = ((const float4*)h1)[0]; p1 = ((const float4*)h1)[1];
        Bh1[nt] = (half8){(_Float16)p0.x, (_Float16)p0.y, (_Float16)p0.z, (_Float16)p0.w,
                          (_Float16)p1.x, (_Float16)p1.y, (_Float16)p1.z, (_Float16)p1.w};
        p0 = ((const float4*)xi)[0]; p1 = ((const float4*)xi)[1];
        Bx[nt]  = (half8){(_Float16)p0.x, (_Float16)p0.y, (_Float16)p0.z, (_Float16)p0.w,
                          (_Float16)p1.x, (_Float16)p1.y, (_Float16)p1.z, (_Float16)p1.w};
    }

    if (tid < 2 * HD) ((_Float16*)zbuf[0])[tid] = (_Float16)0.0f;

    // x: lane reads its A-row's x chunk x[r0+abr][t][lq*8 .. +8)
    const _Float16* xfb = xf + ((size_t)(r0 + abr) * TT) * ID + lq * 8;
    const float*    x32 = x  + ((size_t)(r0 + abr) * TT) * ID + lq * 8;
    half8 xa;
    if (XF16) {
        xa = *(const half8*)xfb;
    } else {
        float4 a = ((const float4*)x32)[0], b = ((const float4*)x32)[1];
        xa = (half8){(_Float16)a.x, (_Float16)a.y, (_Float16)a.z, (_Float16)a.w,
                     (_Float16)b.x, (_Float16)b.y, (_Float16)b.z, (_Float16)b.w};
    }

    float c_ = 0.0f, h_ = 0.0f;
    __syncthreads();

    for (int t = 0; t < TT; ++t) {
        const int cur = t & 1;

        half8 A2 = xa;
        {   // prefetch next x
            const int tn = (t + 1 < TT) ? (t + 1) : t;
            if (XF16) {
                xa = *(const half8*)(xfb + (size_t)tn * ID);
            } else {
                float4 a = ((const float4*)(x32 + (size_t)tn * ID))[0];
                float4 b = ((const float4*)(x32 + (size_t)tn * ID))[1];
                xa = (half8){(_Float16)a.x, (_Float16)a.y, (_Float16)a.z, (_Float16)a.w,
                             (_Float16)b.x, (_Float16)b.y, (_Float16)b.z, (_Float16)b.w};
            }
        }

        // h fragments for this lane's A-row
        half8 A0 = *(const half8*)&zbuf[cur][abr][lq * 8];
        half8 A1 = *(const half8*)&zbuf[cur][abr][32 + lq * 8];

        f32x4 acc[4];
        #pragma unroll
        for (int nt = 0; nt < 4; ++nt)   // x-part first: no LDS dependency
            acc[nt] = __builtin_amdgcn_mfma_f32_16x16x32_f16(A2, Bx[nt], biasC[nt], 0, 0, 0);
        #pragma unroll
        for (int nt = 0; nt < 4; ++nt)
            acc[nt] = __builtin_amdgcn_mfma_f32_16x16x32_f16(A0, Bh0[nt], acc[nt], 0, 0, 0);
        #pragma unroll
        for (int nt = 0; nt < 4; ++nt)
            acc[nt] = __builtin_amdgcn_mfma_f32_16x16x32_f16(A1, Bh1[nt], acc[nt], 0, 0, 0);

        // reg 0 of C row-block lq*4 is batch row lq>>1 (rows duplicated in pairs)
        const float ig = sigm(acc[0][0]);
        const float fg = sigm(acc[1][0]);
        const float gg = tanhfast(acc[2][0]);
        const float og = sigm(acc[3][0]);
        c_ = fmaf(fg, c_, ig * gg);
        h_ = og * tanhfast(c_);

        if (!(lq & 1)) zbuf[cur ^ 1][cbr][wv * 16 + l15] = (_Float16)h_;  // lq 0,2 write
        __syncthreads();
    }

    if (!(lq & 1)) hfin[cbr][wv * 16 + l15] = h_;
    __syncthreads();

    // FC head: waves 0,1 handle rows 0,1. lane: tk=l&7 ticker, q=l>>3 h-chunk.
    if (tid < 128) {
        const int rr = tid >> 6;
        const int tk = l & 7;
        const int q  = l >> 3;
        const float* wf = w_fc + tk * HD + q * 8;
        const float* hv = &hfin[rr][q * 8];
        float a = 0.0f;
        #pragma unroll
        for (int j2 = 0; j2 < 8; ++j2) a = fmaf(hv[j2], wf[j2], a);
        a += __shfl_xor(a, 8);
        a += __shfl_xor(a, 16);
        a += __shfl_xor(a, 32);
        if (q == 0) out[(r0 + rr) * NTK + tk] = a + b_fc[tk];
    }
}

extern "C" void kernel_launch(void* const* d_in, const int* in_sizes, int n_in,
                              void* d_out, int out_size, void* d_ws, size_t ws_size,
                              hipStream_t stream) {
    const float* x    = (const float*)d_in[0];
    const float* w_ih = (const float*)d_in[1];
    const float* w_hh = (const float*)d_in[2];
    const float* b_ih = (const float*)d_in[3];
    const float* b_hh = (const float*)d_in[4];
    const float* w_fc = (const float*)d_in[5];
    const float* b_fc = (const float*)d_in[6];
    float* out = (float*)d_out;

    const int nx = in_sizes[0];              // B*T*I
    const int B  = nx / (TT * ID);           // 512
    const size_t need = (size_t)nx * sizeof(_Float16);

    if (ws_size >= need) {
        _Float16* xf = (_Float16*)d_ws;
        const int n8 = nx / 8;
        cvt_x<<<dim3((n8 + 255) / 256), dim3(256), 0, stream>>>(x, xf, n8);
        lstm_mfma2<true><<<dim3(B / 2), dim3(256), 0, stream>>>(x, xf, w_ih, w_hh,
                                                                b_ih, b_hh, w_fc, b_fc, out);
    } else {
        lstm_mfma2<false><<<dim3(B / 2), dim3(256), 0, stream>>>(x, (const _Float16*)d_ws,
                                                                 w_ih, w_hh, b_ih, b_hh,
                                                                 w_fc, b_fc, out);
    }
}